// Round 16
// baseline (180.905 us; speedup 1.0000x reference)
//
#include <hip/hip_runtime.h>
#include <stdint.h>

#define S_LEN 2048
#define EMB 2048
#define NHEADS 32
#define NKVH 8
#define HDIM 64

typedef float f32x4 __attribute__((ext_vector_type(4)));
typedef float f32x16 __attribute__((ext_vector_type(16)));
typedef __bf16 bf16x8 __attribute__((ext_vector_type(8)));
typedef unsigned int u32x4 __attribute__((ext_vector_type(4)));

typedef const __attribute__((address_space(1))) void* as1cv;
typedef __attribute__((address_space(3))) void* as3v;

__device__ __forceinline__ void gload_lds16(const void* g, void* l) {
  as1cv gp = (as1cv)(uintptr_t)g;
  as3v lp = (as3v)(uintptr_t)l;
  __builtin_amdgcn_global_load_lds(gp, lp, 16, 0, 0);
}

__device__ __forceinline__ unsigned cvt_pk_bf16(float lo, float hi) {
  unsigned r;
  asm("v_cvt_pk_bf16_f32 %0, %1, %2" : "=v"(r) : "v"(lo), "v"(hi));
  return r;
}

__device__ __forceinline__ void permswap(unsigned& a, unsigned& b) {
  asm("v_permlane32_swap_b32 %0, %1" : "+v"(a), "+v"(b));
}

__device__ __forceinline__ bf16x8 pack4(unsigned a, unsigned b, unsigned c, unsigned d) {
  union { u32x4 u; bf16x8 f; } x;
  x.u = (u32x4){a, b, c, d};
  return x.f;
}

// ------- fused preprocessing: cast x->bf16 + 4 transpose-casts + RoPE table ----------
__global__ __launch_bounds__(256) void prep_kernel(const float* __restrict__ x,
                                                   __bf16* __restrict__ xb,
                                                   const float* __restrict__ Wq,
                                                   const float* __restrict__ Wk,
                                                   const float* __restrict__ Wv,
                                                   const float* __restrict__ Wo,
                                                   __bf16* __restrict__ Wcat,
                                                   __bf16* __restrict__ Wot,
                                                   float* __restrict__ cosT,
                                                   float* __restrict__ sinT) {
  int bid = blockIdx.x;
  int tid = threadIdx.x;
  if (bid < 4096) {
    int i = bid * 256 + tid;
    f32x4 a = *(const f32x4*)(x + (size_t)i * 8);
    f32x4 b = *(const f32x4*)(x + (size_t)i * 8 + 4);
    bf16x8 o;
    o[0] = (__bf16)a[0]; o[1] = (__bf16)a[1]; o[2] = (__bf16)a[2]; o[3] = (__bf16)a[3];
    o[4] = (__bf16)b[0]; o[5] = (__bf16)b[1]; o[6] = (__bf16)b[2]; o[7] = (__bf16)b[3];
    *(bf16x8*)(xb + (size_t)i * 8) = o;
    return;
  }
  if (bid >= 6656) {  // RoPE table
    int p = (bid - 6656) * 4 + (tid >> 6);
    int i = tid & 63;
    if (i < 32) {
      float inv = powf(10000.0f, -(float)i / 32.0f);
      float ang = (float)p * inv;
      cosT[p * 32 + i] = cosf(ang);
      sinT[p * 32 + i] = sinf(ang);
    }
    return;
  }
  int lb = bid - 4096;
  const float* in;
  __bf16* out;
  int C, bx, by;
  if (lb < 1024) {
    in = Wq; out = Wcat; C = 2048; bx = lb & 31; by = lb >> 5;
  } else if (lb < 1280) {
    lb -= 1024;
    in = Wk; out = Wcat + (size_t)2048 * 2048; C = 512; bx = lb & 7; by = lb >> 3;
  } else if (lb < 1536) {
    lb -= 1280;
    in = Wv; out = Wcat + (size_t)2560 * 2048; C = 512; bx = lb & 7; by = lb >> 3;
  } else {
    lb -= 1536;
    in = Wo; out = Wot; C = 2048; bx = lb & 31; by = lb >> 5;
  }
  const int R = 2048;
  __shared__ float t[64][65];
  int c0 = bx * 64, r0 = by * 64;
#pragma unroll
  for (int i = 0; i < 16; ++i) {
    int e = i * 256 + tid;
    int rr = e >> 6, cc = e & 63;
    t[rr][cc] = in[(size_t)(r0 + rr) * C + c0 + cc];
  }
  __syncthreads();
#pragma unroll
  for (int i = 0; i < 16; ++i) {
    int e = i * 256 + tid;
    int rr = e >> 6, cc = e & 63;
    out[(size_t)(c0 + rr) * R + r0 + cc] = (__bf16)t[cc][rr];
  }
}

// ====== 4-wave, 2-blocks/CU, 2-phase dbuf bf16 TN GEMM (512-WG grids) ======
template <int BM, int BN, typename OUT>
__global__ __launch_bounds__(256, 2) void gemm4w_kernel(const __bf16* __restrict__ A,
                                                        const __bf16* __restrict__ B,
                                                        OUT* __restrict__ C,
                                                        int M, int N, int K) {
  constexpr int MF = (BM / 2) / 16;
  constexpr int NF = (BN / 2) / 16;
  constexpr int ROWS = BM + BN;
  constexpr int NCALL = ROWS / 32;
  constexpr int CHA = BM / 32;
  __shared__ __align__(16) __bf16 sm[2][ROWS * 64];

  const int NT = K >> 6;
  const int nt = N / BN;
  const int nwg = (M / BM) * nt;
  const int q8 = nwg >> 3;
  int wg = blockIdx.x;
  int swz = (wg & 7) * q8 + (wg >> 3);
  int bm = swz / nt, bn = swz % nt;
  size_t m0 = (size_t)bm * BM, n0 = (size_t)bn * BN;

  int tid = threadIdx.x;
  int L = tid & 63, w = tid >> 6;
  int wrow = w >> 1, wcol = w & 1;
  int l15 = L & 15, hi2 = L >> 4;
  int lx = (l15 & 7) << 4;
  const int cx0 = (hi2 << 4) ^ lx;
  const int cx1 = (64 + (hi2 << 4)) ^ lx;

  int srow = tid >> 3;
  int scol = ((tid & 7) ^ (srow & 7)) << 3;
  const __bf16* pA = A + (size_t)(m0 + srow) * K + scol;
  const __bf16* pB = B + (size_t)(n0 + srow) * K + scol;

  char* smb = (char*)sm;
  const int aRow = (wrow * (BM / 2) + l15) * 128;
  const int bRow = (BM + wcol * (BN / 2) + l15) * 128;

  f32x4 acc[MF][NF];
#pragma unroll
  for (int m = 0; m < MF; ++m)
#pragma unroll
    for (int n = 0; n < NF; ++n) acc[m][n] = (f32x4){0.f, 0.f, 0.f, 0.f};

  auto STG = [&](int buf, int c, int t) {
    const __bf16* s = (c < CHA) ? pA + (size_t)(c << 5) * K + ((size_t)t << 6)
                                : pB + (size_t)((c - CHA) << 5) * K + ((size_t)t << 6);
    gload_lds16(s, smb + buf * (ROWS * 128) + c * 4096 + tid * 16);
  };

#pragma unroll
  for (int c = 0; c < NCALL; ++c) STG(0, c, 0);
#pragma unroll
  for (int c = 0; c < NCALL; ++c) STG(1, c, 1);
  if constexpr (NCALL == 10) asm volatile("s_waitcnt vmcnt(10)" ::: "memory");
  else asm volatile("s_waitcnt vmcnt(8)" ::: "memory");
  __builtin_amdgcn_s_barrier();

  for (int t = 0; t < NT; ++t) {
    const char* aC = smb + (t & 1) * (ROWS * 128);
    bf16x8 af[MF][2], bf[NF][2];
#pragma unroll
    for (int n = 0; n < NF; ++n) {
      bf[n][0] = *(const bf16x8*)(aC + bRow + n * 2048 + cx0);
      bf[n][1] = *(const bf16x8*)(aC + bRow + n * 2048 + cx1);
    }
#pragma unroll
    for (int m = 0; m < MF; ++m) {
      af[m][0] = *(const bf16x8*)(aC + aRow + m * 2048 + cx0);
      af[m][1] = *(const bf16x8*)(aC + aRow + m * 2048 + cx1);
    }
    asm volatile("s_waitcnt lgkmcnt(4)" ::: "memory");
    __builtin_amdgcn_sched_barrier(0);
    __builtin_amdgcn_s_setprio(1);
#pragma unroll
    for (int m = 0; m < MF / 2; ++m)
#pragma unroll
      for (int n = 0; n < NF; ++n)
#pragma unroll
        for (int kk = 0; kk < 2; ++kk)
          acc[m][n] = __builtin_amdgcn_mfma_f32_16x16x32_bf16(
              kk ? af[m][1] : af[m][0], kk ? bf[n][1] : bf[n][0], acc[m][n], 0, 0, 0);
    __builtin_amdgcn_s_setprio(0);
    asm volatile("s_waitcnt lgkmcnt(0)" ::: "memory");
    __builtin_amdgcn_sched_barrier(0);
    __builtin_amdgcn_s_barrier();
    if (t + 2 < NT) {
#pragma unroll
      for (int c = 0; c < NCALL; ++c) STG(t & 1, c, t + 2);
    }
    __builtin_amdgcn_s_setprio(1);
#pragma unroll
    for (int m = MF / 2; m < MF; ++m)
#pragma unroll
      for (int n = 0; n < NF; ++n)
#pragma unroll
        for (int kk = 0; kk < 2; ++kk)
          acc[m][n] = __builtin_amdgcn_mfma_f32_16x16x32_bf16(
              kk ? af[m][1] : af[m][0], kk ? bf[n][1] : bf[n][0], acc[m][n], 0, 0, 0);
    __builtin_amdgcn_s_setprio(0);
    if (t + 2 < NT) {
      if constexpr (NCALL == 10) asm volatile("s_waitcnt vmcnt(10)" ::: "memory");
      else asm volatile("s_waitcnt vmcnt(8)" ::: "memory");
    } else if (t + 1 < NT) {
      asm volatile("s_waitcnt vmcnt(0)" ::: "memory");
    }
    __builtin_amdgcn_s_barrier();
  }

#pragma unroll
  for (int m = 0; m < MF; ++m)
#pragma unroll
    for (int n = 0; n < NF; ++n)
#pragma unroll
      for (int r = 0; r < 4; ++r)
        C[(m0 + wrow * (BM / 2) + m * 16 + (hi2 << 2) + r) * (size_t)N + n0 +
          wcol * (BN / 2) + n * 16 + l15] = (OUT)acc[m][n][r];
}

// ---------------- K/V RMSNorm + RoPE + layout (Q handled inside attention) ------------
__global__ __launch_bounds__(256) void kvrope_kernel(
    const __bf16* __restrict__ QKV, const int* __restrict__ pos,
    const float* __restrict__ kw,
    const float* __restrict__ cosT, const float* __restrict__ sinT,
    __bf16* __restrict__ Katt, __bf16* __restrict__ Vtatt,
    float* __restrict__ Kc, float* __restrict__ Vc) {
  int token = blockIdx.x;
  int b = token >> 11, s = token & 2047;
  int tid = threadIdx.x, lane = tid & 63, wid = tid >> 6;
  int p = pos[token];
  int i = lane & 31;
  float cs = cosT[p * 32 + i], sn = sinT[p * 32 + i];
  const __bf16* base = QKV + (size_t)token * 3072;
  float kwl = kw[lane];

  for (int g = wid; g < NKVH; g += 4) {
    float v = (float)base[2048 + g * 64 + lane];
    float ss = v * v;
#pragma unroll
    for (int m = 1; m < 64; m <<= 1) ss += __shfl_xor(ss, m);
    float xn = v * rsqrtf(ss * (1.0f / 64.0f) + 1e-6f) * kwl;
    float other = __shfl_xor(xn, 32);
    float o = xn * cs + ((lane < 32) ? -other * sn : other * sn);
    size_t kidx = ((size_t)(b * NKVH + g) * S_LEN + s) * HDIM + lane;
    Katt[kidx] = (__bf16)o;
    Kc[kidx] = o;
  }
  for (int g = wid; g < NKVH; g += 4) {
    float v = (float)base[2560 + g * 64 + lane];
    size_t vidx = ((size_t)(b * NKVH + g) * S_LEN + s) * HDIM + lane;
    Vc[vidx] = v;
    Vtatt[((size_t)(b * NKVH + g) * HDIM + lane) * S_LEN + s] = (__bf16)v;
  }
}

// -------- causal GQA flash attention v9: 2-wave blocks, 4 barrier domains/CU ----------
// Same wave body as the r7/r15 config (shared K/V frags feed both q-subtiles, no-max
// softmax, fused Q prologue). Block = 2 waves = 2 heads; grid 1024; LDS 32KB -> 4
// blocks/CU. Round-robin-256 dispatch gives CU i bids {i,i+256,i+512,i+768} with
// qt = {31-k, k, 23-k, 8+k} (uniform 66 iters/CU) and IDENTICAL (bg,hp) -> K/V L2-local.
// Each SIMD hosts 2 waves from DIFFERENT barrier domains -> phases interleave.
__global__ __launch_bounds__(128, 2) void attn_kernel(const __bf16* __restrict__ QKV,
                                                      const int* __restrict__ pos,
                                                      const float* __restrict__ qw,
                                                      const float* __restrict__ cosT,
                                                      const float* __restrict__ sinT,
                                                      const __bf16* __restrict__ Katt,
                                                      const __bf16* __restrict__ Vtatt,
                                                      __bf16* __restrict__ ctx) {
  __shared__ __align__(16) __bf16 Ks[2][4096];
  __shared__ __align__(16) __bf16 Vs[2][4096];
  int bid = blockIdx.x;
  int seg = bid >> 8, k = (bid & 255) >> 5, combo = bid & 31;
  int qt = (seg == 0) ? (31 - k) : (seg == 1) ? k : (seg == 2) ? (23 - k) : (8 + k);
  int bg = combo >> 1, hp = combo & 1;
  int b = bg >> 3, g = bg & 7;
  int tid = threadIdx.x, lane = tid & 63, w = tid >> 6;  // w in {0,1}
  int l31 = lane & 31, hi = lane >> 5;
  int h = g * 4 + hp * 2 + w;

  const __bf16* Kg = Katt + (size_t)bg * (S_LEN * HDIM);
  const __bf16* Vg = Vtatt + (size_t)bg * (HDIM * S_LEN);

  // staging pointers: 128 threads, 8 gload calls/tile (4 K + 4 V, 16 rows each)
  int sr = tid >> 3;                           // 0..15
  int sc = ((tid & 7) ^ (sr & 7)) << 3;
  const __bf16* Ksrc = Kg + (size_t)sr * HDIM + sc;
  const __bf16* Vsrc = Vg + (size_t)sr * S_LEN + sc;

  // issue tile-0 staging FIRST so HBM latency hides under the Q prologue
#pragma unroll
  for (int c = 0; c < 4; ++c) {
    gload_lds16(Ksrc + c * 16 * HDIM, &Ks[0][c * 1024 + tid * 8]);
    gload_lds16(Vsrc + (size_t)(c * 16) * S_LEN, &Vs[0][c * 1024 + tid * 8]);
  }

  // ---- fused Q prologue: raw QKV -> normalized, roped, scaled bf16 B-fragments ----
  const float qscale = 0.18033688011112042f;  // 0.125 * log2(e)
  float qwf[4][8];
#pragma unroll
  for (int ds = 0; ds < 4; ++ds) {
    *(f32x4*)&qwf[ds][0] = *(const f32x4*)(qw + ds * 16 + (hi << 3));
    *(f32x4*)&qwf[ds][4] = *(const f32x4*)(qw + ds * 16 + (hi << 3) + 4);
  }
  bf16x8 qf[2][4];
#pragma unroll
  for (int qs = 0; qs < 2; ++qs) {
    int row = qt * 64 + qs * 32 + l31;
    const __bf16* qr = QKV + ((size_t)(b * S_LEN + row)) * 3072 + h * 64;
    float v[4][8];
    float ss = 0.f;
#pragma unroll
    for (int ds = 0; ds < 4; ++ds) {
      bf16x8 a = *(const bf16x8*)(qr + ds * 16 + (hi << 3));
#pragma unroll
      for (int j = 0; j < 8; ++j) {
        v[ds][j] = (float)a[j];
        ss += v[ds][j] * v[ds][j];
      }
    }
    ss += __shfl_xor(ss, 32);
    float rr = rsqrtf(ss * (1.0f / 64.0f) + 1e-6f) * qscale;
    int p = pos[b * S_LEN + row];
    const float* cb = cosT + p * 32 + (hi << 3);
    const float* sb = sinT + p * 32 + (hi << 3);
    float cl[8], ch[8], sl[8], sh[8];
    *(f32x4*)&cl[0] = *(const f32x4*)cb;        *(f32x4*)&cl[4] = *(const f32x4*)(cb + 4);
    *(f32x4*)&ch[0] = *(const f32x4*)(cb + 16); *(f32x4*)&ch[4] = *(const f32x4*)(cb + 20);
    *(f32x4*)&sl[0] = *(const f32x4*)sb;        *(f32x4*)&sl[4] = *(const f32x4*)(sb + 4);
    *(f32x4*)&sh[0] = *(const f32x4*)(sb + 16); *(f32x4*)&sh[4] = *(const f32x4*)(sb + 20);
    float o[4][8];
#pragma unroll
    for (int j = 0; j < 8; ++j) {
      float x0 = v[0][j] * rr * qwf[0][j];
      float x1 = v[1][j] * rr * qwf[1][j];
      float x2 = v[2][j] * rr * qwf[2][j];
      float x3 = v[3][j] * rr * qwf[3][j];
      o[0][j] = x0 * cl[j] - x2 * sl[j];
      o[1][j] = x1 * ch[j] - x3 * sh[j];
      o[2][j] = x2 * cl[j] + x0 * sl[j];
      o[3][j] = x3 * ch[j] + x1 * sh[j];
    }
#pragma unroll
    for (int ds = 0; ds < 4; ++ds)
      qf[qs][ds] = pack4(cvt_pk_bf16(o[ds][0], o[ds][1]), cvt_pk_bf16(o[ds][2], o[ds][3]),
                         cvt_pk_bf16(o[ds][4], o[ds][5]), cvt_pk_bf16(o[ds][6], o[ds][7]));
  }

  f32x16 acc00, acc01, acc10, acc11;  // [qsub][dblock], O^T[d][q]
#pragma unroll
  for (int r = 0; r < 16; ++r) { acc00[r] = 0.f; acc01[r] = 0.f; acc10[r] = 0.f; acc11[r] = 0.f; }
  float l0 = 0.f, l1 = 0.f;

  __syncthreads();

  int rx = (l31 & 7) << 4;

  for (int t = 0; t <= qt; ++t) {
    int cur = t & 1;
    if (t < qt) {
      const __bf16* kn = Ksrc + (size_t)(t + 1) * (64 * HDIM);
      const __bf16* vn = Vsrc + (size_t)(t + 1) * 64;
#pragma unroll
      for (int c = 0; c < 4; ++c) {
        gload_lds16(kn + c * 16 * HDIM, &Ks[cur ^ 1][c * 1024 + tid * 8]);
        gload_lds16(vn + (size_t)(c * 16) * S_LEN, &Vs[cur ^ 1][c * 1024 + tid * 8]);
      }
    }
    // QK^T swapped: S^T[kv][q] = K x Q ; shared K-frag reads feed both q-subtiles
    f32x16 s00, s01, s10, s11;
#pragma unroll
    for (int r = 0; r < 16; ++r) { s00[r] = 0.f; s01[r] = 0.f; s10[r] = 0.f; s11[r] = 0.f; }
    {
      const char* kb0 = (const char*)Ks[cur] + (size_t)l31 * 128;
      const char* kb1 = kb0 + 4096;
#pragma unroll
      for (int dstep = 0; dstep < 4; ++dstep) {
        int cb = dstep * 32 + (hi << 4);
        bf16x8 k0 = *(const bf16x8*)(kb0 + (cb ^ rx));
        bf16x8 k1 = *(const bf16x8*)(kb1 + (cb ^ rx));
        s00 = __builtin_amdgcn_mfma_f32_32x32x16_bf16(k0, qf[0][dstep], s00, 0, 0, 0);
        s01 = __builtin_amdgcn_mfma_f32_32x32x16_bf16(k1, qf[0][dstep], s01, 0, 0, 0);
        s10 = __builtin_amdgcn_mfma_f32_32x32x16_bf16(k0, qf[1][dstep], s10, 0, 0, 0);
        s11 = __builtin_amdgcn_mfma_f32_32x32x16_bf16(k1, qf[1][dstep], s11, 0, 0, 0);
      }
    }
    if (t == qt) {  // diagonal tile masks
#pragma unroll
      for (int r = 0; r < 16; ++r) {
        int kb = (r & 3) + 8 * (r >> 2) + (hi << 2);
        if (kb > l31) { s00[r] = -3e38f; s11[r] = -3e38f; }
        s01[r] = -3e38f;
      }
    }
#pragma unroll
    for (int r = 0; r < 16; ++r) {
      s00[r] = __builtin_amdgcn_exp2f(s00[r]);
      s01[r] = __builtin_amdgcn_exp2f(s01[r]);
      s10[r] = __builtin_amdgcn_exp2f(s10[r]);
      s11[r] = __builtin_amdgcn_exp2f(s11[r]);
    }
    {
      float a0 = 0.f, a1 = 0.f, a2 = 0.f, a3 = 0.f;
      float b0 = 0.f, b1 = 0.f, b2 = 0.f, b3 = 0.f;
#pragma unroll
      for (int r = 0; r < 16; r += 4) {
        a0 += s00[r]; a1 += s00[r + 1]; a2 += s00[r + 2]; a3 += s00[r + 3];
        a0 += s01[r]; a1 += s01[r + 1]; a2 += s01[r + 2]; a3 += s01[r + 3];
        b0 += s10[r]; b1 += s10[r + 1]; b2 += s10[r + 2]; b3 += s10[r + 3];
        b0 += s11[r]; b1 += s11[r + 1]; b2 += s11[r + 2]; b3 += s11[r + 3];
      }
      l0 += (a0 + a1) + (a2 + a3);
      l1 += (b0 + b1) + (b2 + b3);
    }
    bf16x8 pf0[4], pf1[4];
    {
      unsigned wd[8];
#pragma unroll
      for (int i = 0; i < 8; ++i) wd[i] = cvt_pk_bf16(s00[2 * i], s00[2 * i + 1]);
      permswap(wd[0], wd[2]); permswap(wd[1], wd[3]);
      permswap(wd[4], wd[6]); permswap(wd[5], wd[7]);
      pf0[0] = pack4(wd[0], wd[1], wd[2], wd[3]);
      pf0[1] = pack4(wd[4], wd[5], wd[6], wd[7]);
#pragma unroll
      for (int i = 0; i < 8; ++i) wd[i] = cvt_pk_bf16(s01[2 * i], s01[2 * i + 1]);
      permswap(wd[0], wd[2]); permswap(wd[1], wd[3]);
      permswap(wd[4], wd[6]); permswap(wd[5], wd[7]);
      pf0[2] = pack4(wd[0], wd[1], wd[2], wd[3]);
      pf0[3] = pack4(wd[4], wd[5], wd[6], wd[7]);
#pragma unroll
      for (int i = 0; i < 8; ++i) wd[i] = cvt_pk_bf16(s10[2 * i], s10[2 * i + 1]);
      permswap(wd[0], wd[2]); permswap(wd[1], wd[3]);
      permswap(wd[4], wd[6]); permswap(wd[5], wd[7]);
      pf1[0] = pack4(wd[0], wd[1], wd[2], wd[3]);
      pf1[1] = pack4(wd[4], wd[5], wd[6], wd[7]);
#pragma unroll
      for (int i = 0; i < 8; ++i) wd[i] = cvt_pk_bf16(s11[2 * i], s11[2 * i + 1]);
      permswap(wd[0], wd[2]); permswap(wd[1], wd[3]);
      permswap(wd[4], wd[6]); permswap(wd[5], wd[7]);
      pf1[2] = pack4(wd[0], wd[1], wd[2], wd[3]);
      pf1[3] = pack4(wd[4], wd[5], wd[6], wd[7]);
    }
    {
      const char* vb0 = (const char*)Vs[cur] + (size_t)l31 * 128;
      const char* vb1 = vb0 + 4096;
#pragma unroll
      for (int ks = 0; ks < 4; ++ks) {
        int cb = ks * 32 + (hi << 4);
        bf16x8 v0 = *(const bf16x8*)(vb0 + (cb ^ rx));
        bf16x8 v1 = *(const bf16x8*)(vb1 + (cb ^ rx));
        acc00 = __builtin_amdgcn_mfma_f32_32x32x16_bf16(v0, pf0[ks], acc00, 0, 0, 0);
        acc01 = __builtin_amdgcn_mfma_f32_32x32x16_bf16(v1, pf0[ks], acc01, 0, 0, 0);
        acc10 = __builtin_amdgcn_mfma_f32_32x32x16_bf16(v0, pf1[ks], acc10, 0, 0, 0);
        acc11 = __builtin_amdgcn_mfma_f32_32x32x16_bf16(v1, pf1[ks], acc11, 0, 0, 0);
      }
    }
    __syncthreads();
  }

  l0 += __shfl_xor(l0, 32);
  l1 += __shfl_xor(l1, 32);
  float inv0 = 1.f / l0, inv1 = 1.f / l1;
  size_t orow0 = ((size_t)(b * S_LEN + qt * 64 + l31)) * EMB + h * HDIM;
  size_t orow1 = orow0 + (size_t)32 * EMB;
#pragma unroll
  for (int r = 0; r < 16; r += 2) {
    int d = (r & 3) + 8 * (r >> 2) + (hi << 2);
    unsigned w00 = cvt_pk_bf16(acc00[r] * inv0, acc00[r + 1] * inv0);
    unsigned w01 = cvt_pk_bf16(acc01[r] * inv0, acc01[r + 1] * inv0);
    unsigned w10 = cvt_pk_bf16(acc10[r] * inv1, acc10[r + 1] * inv1);
    unsigned w11 = cvt_pk_bf16(acc11[r] * inv1, acc11[r + 1] * inv1);
    *(unsigned*)((char*)ctx + (orow0 + d) * 2) = w00;
    *(unsigned*)((char*)ctx + (orow0 + 32 + d) * 2) = w01;
    *(unsigned*)((char*)ctx + (orow1 + d) * 2) = w10;
    *(unsigned*)((char*)ctx + (orow1 + 32 + d) * 2) = w11;
  }
}

extern "C" void kernel_launch(void* const* d_in, const int* in_sizes, int n_in,
                              void* d_out, int out_size, void* d_ws, size_t ws_size,
                              hipStream_t stream) {
  const float* x = (const float*)d_in[0];
  const int* pos = (const int*)d_in[1];
  const float* Wq = (const float*)d_in[3];
  const float* Wk = (const float*)d_in[4];
  const float* Wv = (const float*)d_in[5];
  const float* Wo = (const float*)d_in[6];
  const float* qw = (const float*)d_in[7];
  const float* kw = (const float*)d_in[8];

  float* out = (float*)d_out;
  float* Kc = out + (size_t)2 * 2048 * 2048;
  float* Vc = Kc + (size_t)2 * 8 * 2048 * 64;

  char* ws = (char*)d_ws;
  size_t off = 0;
  auto alloc = [&](size_t bytes) {
    char* p = ws + off;
    off += (bytes + 255) & ~(size_t)255;
    return (void*)p;
  };
  __bf16* xb = (__bf16*)alloc((size_t)4096 * 2048 * 2);
  __bf16* Wcat = (__bf16*)alloc((size_t)3072 * 2048 * 2);
  __bf16* Wot = (__bf16*)alloc((size_t)2048 * 2048 * 2);
  __bf16* QKV = (__bf16*)alloc((size_t)4096 * 3072 * 2);
  __bf16* ctx = (__bf16*)alloc((size_t)4096 * 2048 * 2);
  __bf16* Katt = (__bf16*)alloc((size_t)2 * 8 * 2048 * 64 * 2);
  __bf16* Vtat = (__bf16*)alloc((size_t)2 * 8 * 2048 * 64 * 2);
  float* cosT = (float*)alloc((size_t)2048 * 32 * 4);
  float* sinT = (float*)alloc((size_t)2048 * 32 * 4);

  prep_kernel<<<7168, 256, 0, stream>>>(x, xb, Wq, Wk, Wv, Wo, Wcat, Wot, cosT, sinT);
  gemm4w_kernel<128, 192, __bf16><<<512, 256, 0, stream>>>(xb, Wcat, QKV, 4096, 3072, 2048);
  kvrope_kernel<<<4096, 256, 0, stream>>>(QKV, pos, kw, cosT, sinT, Katt, Vtat, Kc, Vc);
  attn_kernel<<<1024, 128, 0, stream>>>(QKV, pos, qw, cosT, sinT, Katt, Vtat, ctx);
  gemm4w_kernel<128, 128, float><<<512, 256, 0, stream>>>(ctx, Wot, out, 4096, 2048, 2048);
}

// Round 17
// 168.999 us; speedup vs baseline: 1.0705x; 1.0705x over previous
//
#include <hip/hip_runtime.h>
#include <stdint.h>

#define S_LEN 2048
#define EMB 2048
#define NHEADS 32
#define NKVH 8
#define HDIM 64

typedef float f32x4 __attribute__((ext_vector_type(4)));
typedef float f32x16 __attribute__((ext_vector_type(16)));
typedef __bf16 bf16x8 __attribute__((ext_vector_type(8)));
typedef unsigned int u32x4 __attribute__((ext_vector_type(4)));

typedef const __attribute__((address_space(1))) void* as1cv;
typedef __attribute__((address_space(3))) void* as3v;

__device__ __forceinline__ void gload_lds16(const void* g, void* l) {
  as1cv gp = (as1cv)(uintptr_t)g;
  as3v lp = (as3v)(uintptr_t)l;
  __builtin_amdgcn_global_load_lds(gp, lp, 16, 0, 0);
}

__device__ __forceinline__ unsigned cvt_pk_bf16(float lo, float hi) {
  unsigned r;
  asm("v_cvt_pk_bf16_f32 %0, %1, %2" : "=v"(r) : "v"(lo), "v"(hi));
  return r;
}

__device__ __forceinline__ void permswap(unsigned& a, unsigned& b) {
  asm("v_permlane32_swap_b32 %0, %1" : "+v"(a), "+v"(b));
}

__device__ __forceinline__ bf16x8 pack4(unsigned a, unsigned b, unsigned c, unsigned d) {
  union { u32x4 u; bf16x8 f; } x;
  x.u = (u32x4){a, b, c, d};
  return x.f;
}

// ------- fused preprocessing: cast x->bf16 + 4 transpose-casts + RoPE table ----------
__global__ __launch_bounds__(256) void prep_kernel(const float* __restrict__ x,
                                                   __bf16* __restrict__ xb,
                                                   const float* __restrict__ Wq,
                                                   const float* __restrict__ Wk,
                                                   const float* __restrict__ Wv,
                                                   const float* __restrict__ Wo,
                                                   __bf16* __restrict__ Wcat,
                                                   __bf16* __restrict__ Wot,
                                                   float* __restrict__ cosT,
                                                   float* __restrict__ sinT) {
  int bid = blockIdx.x;
  int tid = threadIdx.x;
  if (bid < 4096) {
    int i = bid * 256 + tid;
    f32x4 a = *(const f32x4*)(x + (size_t)i * 8);
    f32x4 b = *(const f32x4*)(x + (size_t)i * 8 + 4);
    bf16x8 o;
    o[0] = (__bf16)a[0]; o[1] = (__bf16)a[1]; o[2] = (__bf16)a[2]; o[3] = (__bf16)a[3];
    o[4] = (__bf16)b[0]; o[5] = (__bf16)b[1]; o[6] = (__bf16)b[2]; o[7] = (__bf16)b[3];
    *(bf16x8*)(xb + (size_t)i * 8) = o;
    return;
  }
  if (bid >= 6656) {  // RoPE table
    int p = (bid - 6656) * 4 + (tid >> 6);
    int i = tid & 63;
    if (i < 32) {
      float inv = powf(10000.0f, -(float)i / 32.0f);
      float ang = (float)p * inv;
      cosT[p * 32 + i] = cosf(ang);
      sinT[p * 32 + i] = sinf(ang);
    }
    return;
  }
  int lb = bid - 4096;
  const float* in;
  __bf16* out;
  int C, bx, by;
  if (lb < 1024) {
    in = Wq; out = Wcat; C = 2048; bx = lb & 31; by = lb >> 5;
  } else if (lb < 1280) {
    lb -= 1024;
    in = Wk; out = Wcat + (size_t)2048 * 2048; C = 512; bx = lb & 7; by = lb >> 3;
  } else if (lb < 1536) {
    lb -= 1280;
    in = Wv; out = Wcat + (size_t)2560 * 2048; C = 512; bx = lb & 7; by = lb >> 3;
  } else {
    lb -= 1536;
    in = Wo; out = Wot; C = 2048; bx = lb & 31; by = lb >> 5;
  }
  const int R = 2048;
  __shared__ float t[64][65];
  int c0 = bx * 64, r0 = by * 64;
#pragma unroll
  for (int i = 0; i < 16; ++i) {
    int e = i * 256 + tid;
    int rr = e >> 6, cc = e & 63;
    t[rr][cc] = in[(size_t)(r0 + rr) * C + c0 + cc];
  }
  __syncthreads();
#pragma unroll
  for (int i = 0; i < 16; ++i) {
    int e = i * 256 + tid;
    int rr = e >> 6, cc = e & 63;
    out[(size_t)(c0 + rr) * R + r0 + cc] = (__bf16)t[cc][rr];
  }
}

// ====== 4-wave, 2-blocks/CU, 2-phase dbuf bf16 TN GEMM (512-WG grids) ======
template <int BM, int BN, typename OUT>
__global__ __launch_bounds__(256, 2) void gemm4w_kernel(const __bf16* __restrict__ A,
                                                        const __bf16* __restrict__ B,
                                                        OUT* __restrict__ C,
                                                        int M, int N, int K) {
  constexpr int MF = (BM / 2) / 16;
  constexpr int NF = (BN / 2) / 16;
  constexpr int ROWS = BM + BN;
  constexpr int NCALL = ROWS / 32;
  constexpr int CHA = BM / 32;
  __shared__ __align__(16) __bf16 sm[2][ROWS * 64];

  const int NT = K >> 6;
  const int nt = N / BN;
  const int nwg = (M / BM) * nt;
  const int q8 = nwg >> 3;
  int wg = blockIdx.x;
  int swz = (wg & 7) * q8 + (wg >> 3);
  int bm = swz / nt, bn = swz % nt;
  size_t m0 = (size_t)bm * BM, n0 = (size_t)bn * BN;

  int tid = threadIdx.x;
  int L = tid & 63, w = tid >> 6;
  int wrow = w >> 1, wcol = w & 1;
  int l15 = L & 15, hi2 = L >> 4;
  int lx = (l15 & 7) << 4;
  const int cx0 = (hi2 << 4) ^ lx;
  const int cx1 = (64 + (hi2 << 4)) ^ lx;

  int srow = tid >> 3;
  int scol = ((tid & 7) ^ (srow & 7)) << 3;
  const __bf16* pA = A + (size_t)(m0 + srow) * K + scol;
  const __bf16* pB = B + (size_t)(n0 + srow) * K + scol;

  char* smb = (char*)sm;
  const int aRow = (wrow * (BM / 2) + l15) * 128;
  const int bRow = (BM + wcol * (BN / 2) + l15) * 128;

  f32x4 acc[MF][NF];
#pragma unroll
  for (int m = 0; m < MF; ++m)
#pragma unroll
    for (int n = 0; n < NF; ++n) acc[m][n] = (f32x4){0.f, 0.f, 0.f, 0.f};

  auto STG = [&](int buf, int c, int t) {
    const __bf16* s = (c < CHA) ? pA + (size_t)(c << 5) * K + ((size_t)t << 6)
                                : pB + (size_t)((c - CHA) << 5) * K + ((size_t)t << 6);
    gload_lds16(s, smb + buf * (ROWS * 128) + c * 4096 + tid * 16);
  };

#pragma unroll
  for (int c = 0; c < NCALL; ++c) STG(0, c, 0);
#pragma unroll
  for (int c = 0; c < NCALL; ++c) STG(1, c, 1);
  if constexpr (NCALL == 10) asm volatile("s_waitcnt vmcnt(10)" ::: "memory");
  else asm volatile("s_waitcnt vmcnt(8)" ::: "memory");
  __builtin_amdgcn_s_barrier();

  for (int t = 0; t < NT; ++t) {
    const char* aC = smb + (t & 1) * (ROWS * 128);
    bf16x8 af[MF][2], bf[NF][2];
#pragma unroll
    for (int n = 0; n < NF; ++n) {
      bf[n][0] = *(const bf16x8*)(aC + bRow + n * 2048 + cx0);
      bf[n][1] = *(const bf16x8*)(aC + bRow + n * 2048 + cx1);
    }
#pragma unroll
    for (int m = 0; m < MF; ++m) {
      af[m][0] = *(const bf16x8*)(aC + aRow + m * 2048 + cx0);
      af[m][1] = *(const bf16x8*)(aC + aRow + m * 2048 + cx1);
    }
    asm volatile("s_waitcnt lgkmcnt(4)" ::: "memory");
    __builtin_amdgcn_sched_barrier(0);
    __builtin_amdgcn_s_setprio(1);
#pragma unroll
    for (int m = 0; m < MF / 2; ++m)
#pragma unroll
      for (int n = 0; n < NF; ++n)
#pragma unroll
        for (int kk = 0; kk < 2; ++kk)
          acc[m][n] = __builtin_amdgcn_mfma_f32_16x16x32_bf16(
              kk ? af[m][1] : af[m][0], kk ? bf[n][1] : bf[n][0], acc[m][n], 0, 0, 0);
    __builtin_amdgcn_s_setprio(0);
    asm volatile("s_waitcnt lgkmcnt(0)" ::: "memory");
    __builtin_amdgcn_sched_barrier(0);
    __builtin_amdgcn_s_barrier();
    if (t + 2 < NT) {
#pragma unroll
      for (int c = 0; c < NCALL; ++c) STG(t & 1, c, t + 2);
    }
    __builtin_amdgcn_s_setprio(1);
#pragma unroll
    for (int m = MF / 2; m < MF; ++m)
#pragma unroll
      for (int n = 0; n < NF; ++n)
#pragma unroll
        for (int kk = 0; kk < 2; ++kk)
          acc[m][n] = __builtin_amdgcn_mfma_f32_16x16x32_bf16(
              kk ? af[m][1] : af[m][0], kk ? bf[n][1] : bf[n][0], acc[m][n], 0, 0, 0);
    __builtin_amdgcn_s_setprio(0);
    if (t + 2 < NT) {
      if constexpr (NCALL == 10) asm volatile("s_waitcnt vmcnt(10)" ::: "memory");
      else asm volatile("s_waitcnt vmcnt(8)" ::: "memory");
    } else if (t + 1 < NT) {
      asm volatile("s_waitcnt vmcnt(0)" ::: "memory");
    }
    __builtin_amdgcn_s_barrier();
  }

#pragma unroll
  for (int m = 0; m < MF; ++m)
#pragma unroll
    for (int n = 0; n < NF; ++n)
#pragma unroll
      for (int r = 0; r < 4; ++r)
        C[(m0 + wrow * (BM / 2) + m * 16 + (hi2 << 2) + r) * (size_t)N + n0 +
          wcol * (BN / 2) + n * 16 + l15] = (OUT)acc[m][n][r];
}

// ---------------- K/V RMSNorm + RoPE + layout (Q handled inside attention) ------------
__global__ __launch_bounds__(256) void kvrope_kernel(
    const __bf16* __restrict__ QKV, const int* __restrict__ pos,
    const float* __restrict__ kw,
    const float* __restrict__ cosT, const float* __restrict__ sinT,
    __bf16* __restrict__ Katt, __bf16* __restrict__ Vtatt,
    float* __restrict__ Kc, float* __restrict__ Vc) {
  int token = blockIdx.x;
  int b = token >> 11, s = token & 2047;
  int tid = threadIdx.x, lane = tid & 63, wid = tid >> 6;
  int p = pos[token];
  int i = lane & 31;
  float cs = cosT[p * 32 + i], sn = sinT[p * 32 + i];
  const __bf16* base = QKV + (size_t)token * 3072;
  float kwl = kw[lane];

  for (int g = wid; g < NKVH; g += 4) {
    float v = (float)base[2048 + g * 64 + lane];
    float ss = v * v;
#pragma unroll
    for (int m = 1; m < 64; m <<= 1) ss += __shfl_xor(ss, m);
    float xn = v * rsqrtf(ss * (1.0f / 64.0f) + 1e-6f) * kwl;
    float other = __shfl_xor(xn, 32);
    float o = xn * cs + ((lane < 32) ? -other * sn : other * sn);
    size_t kidx = ((size_t)(b * NKVH + g) * S_LEN + s) * HDIM + lane;
    Katt[kidx] = (__bf16)o;
    Kc[kidx] = o;
  }
  for (int g = wid; g < NKVH; g += 4) {
    float v = (float)base[2560 + g * 64 + lane];
    size_t vidx = ((size_t)(b * NKVH + g) * S_LEN + s) * HDIM + lane;
    Vc[vidx] = v;
    Vtatt[((size_t)(b * NKVH + g) * HDIM + lane) * S_LEN + s] = (__bf16)v;
  }
}

// ---------------- causal GQA flash attention + fused Q RMSNorm/RoPE prologue ----------
// r15 config (best measured) with ONE change: tile-0 K/V staging is issued BEFORE the
// Q prologue so the first HBM fetch hides under prologue compute.
__global__ __launch_bounds__(256, 2) void attn_kernel(const __bf16* __restrict__ QKV,
                                                      const int* __restrict__ pos,
                                                      const float* __restrict__ qw,
                                                      const float* __restrict__ cosT,
                                                      const float* __restrict__ sinT,
                                                      const __bf16* __restrict__ Katt,
                                                      const __bf16* __restrict__ Vtatt,
                                                      __bf16* __restrict__ ctx) {
  __shared__ __align__(16) __bf16 Ks[2][4096];
  __shared__ __align__(16) __bf16 Vs[2][4096];
  int bid = blockIdx.x;
  int qt, bg;
  if (bid < 256) { qt = 31 - (bid >> 4); bg = bid & 15; }  // CU gets qt pair summing 31
  else { qt = (bid - 256) >> 4; bg = bid & 15; }
  int b = bg >> 3, g = bg & 7;
  int tid = threadIdx.x, lane = tid & 63, w = tid >> 6;
  int l31 = lane & 31, hi = lane >> 5;
  int h = g * 4 + w;

  const __bf16* Kg = Katt + (size_t)bg * (S_LEN * HDIM);
  const __bf16* Vg = Vtatt + (size_t)bg * (HDIM * S_LEN);

  // staging pointers + issue tile-0 FIRST (HBM latency hides under Q prologue)
  int sr = tid >> 3;
  int sc = ((tid & 7) ^ (sr & 7)) << 3;
  const __bf16* Ksrc = Kg + (size_t)sr * HDIM + sc;
  const __bf16* Vsrc = Vg + (size_t)sr * S_LEN + sc;

  gload_lds16(Ksrc, &Ks[0][tid * 8]);
  gload_lds16(Ksrc + 32 * HDIM, &Ks[0][2048 + tid * 8]);
  gload_lds16(Vsrc, &Vs[0][tid * 8]);
  gload_lds16(Vsrc + (size_t)32 * S_LEN, &Vs[0][2048 + tid * 8]);

  // ---- fused Q prologue: raw QKV -> normalized, roped, scaled bf16 B-fragments ----
  const float qscale = 0.18033688011112042f;  // 0.125 * log2(e)
  float qwf[4][8];
#pragma unroll
  for (int ds = 0; ds < 4; ++ds) {
    *(f32x4*)&qwf[ds][0] = *(const f32x4*)(qw + ds * 16 + (hi << 3));
    *(f32x4*)&qwf[ds][4] = *(const f32x4*)(qw + ds * 16 + (hi << 3) + 4);
  }
  bf16x8 qf[2][4];
#pragma unroll
  for (int qs = 0; qs < 2; ++qs) {
    int row = qt * 64 + qs * 32 + l31;
    const __bf16* qr = QKV + ((size_t)(b * S_LEN + row)) * 3072 + h * 64;
    float v[4][8];
    float ss = 0.f;
#pragma unroll
    for (int ds = 0; ds < 4; ++ds) {
      bf16x8 a = *(const bf16x8*)(qr + ds * 16 + (hi << 3));
#pragma unroll
      for (int j = 0; j < 8; ++j) {
        v[ds][j] = (float)a[j];
        ss += v[ds][j] * v[ds][j];
      }
    }
    ss += __shfl_xor(ss, 32);
    float rr = rsqrtf(ss * (1.0f / 64.0f) + 1e-6f) * qscale;
    int p = pos[b * S_LEN + row];
    const float* cb = cosT + p * 32 + (hi << 3);
    const float* sb = sinT + p * 32 + (hi << 3);
    float cl[8], ch[8], sl[8], sh[8];
    *(f32x4*)&cl[0] = *(const f32x4*)cb;        *(f32x4*)&cl[4] = *(const f32x4*)(cb + 4);
    *(f32x4*)&ch[0] = *(const f32x4*)(cb + 16); *(f32x4*)&ch[4] = *(const f32x4*)(cb + 20);
    *(f32x4*)&sl[0] = *(const f32x4*)sb;        *(f32x4*)&sl[4] = *(const f32x4*)(sb + 4);
    *(f32x4*)&sh[0] = *(const f32x4*)(sb + 16); *(f32x4*)&sh[4] = *(const f32x4*)(sb + 20);
    float o[4][8];
#pragma unroll
    for (int j = 0; j < 8; ++j) {
      float x0 = v[0][j] * rr * qwf[0][j];
      float x1 = v[1][j] * rr * qwf[1][j];
      float x2 = v[2][j] * rr * qwf[2][j];
      float x3 = v[3][j] * rr * qwf[3][j];
      o[0][j] = x0 * cl[j] - x2 * sl[j];
      o[1][j] = x1 * ch[j] - x3 * sh[j];
      o[2][j] = x2 * cl[j] + x0 * sl[j];
      o[3][j] = x3 * ch[j] + x1 * sh[j];
    }
#pragma unroll
    for (int ds = 0; ds < 4; ++ds)
      qf[qs][ds] = pack4(cvt_pk_bf16(o[ds][0], o[ds][1]), cvt_pk_bf16(o[ds][2], o[ds][3]),
                         cvt_pk_bf16(o[ds][4], o[ds][5]), cvt_pk_bf16(o[ds][6], o[ds][7]));
  }

  f32x16 acc00, acc01, acc10, acc11;  // [qsub][dblock], O^T[d][q]
#pragma unroll
  for (int r = 0; r < 16; ++r) { acc00[r] = 0.f; acc01[r] = 0.f; acc10[r] = 0.f; acc11[r] = 0.f; }
  float l0 = 0.f, l1 = 0.f;

  __syncthreads();

  int rx = (l31 & 7) << 4;

  for (int t = 0; t <= qt; ++t) {
    int cur = t & 1;
    if (t < qt) {
      const __bf16* kn = Ksrc + (size_t)(t + 1) * (64 * HDIM);
      const __bf16* vn = Vsrc + (size_t)(t + 1) * 64;
      gload_lds16(kn, &Ks[cur ^ 1][tid * 8]);
      gload_lds16(kn + 32 * HDIM, &Ks[cur ^ 1][2048 + tid * 8]);
      gload_lds16(vn, &Vs[cur ^ 1][tid * 8]);
      gload_lds16(vn + (size_t)32 * S_LEN, &Vs[cur ^ 1][2048 + tid * 8]);
    }
    // QK^T swapped: S^T[kv][q] = K x Q ; shared K-frag reads feed both q-subtiles
    f32x16 s00, s01, s10, s11;
#pragma unroll
    for (int r = 0; r < 16; ++r) { s00[r] = 0.f; s01[r] = 0.f; s10[r] = 0.f; s11[r] = 0.f; }
    {
      const char* kb0 = (const char*)Ks[cur] + (size_t)l31 * 128;
      const char* kb1 = kb0 + 4096;
#pragma unroll
      for (int dstep = 0; dstep < 4; ++dstep) {
        int cb = dstep * 32 + (hi << 4);
        bf16x8 k0 = *(const bf16x8*)(kb0 + (cb ^ rx));
        bf16x8 k1 = *(const bf16x8*)(kb1 + (cb ^ rx));
        s00 = __builtin_amdgcn_mfma_f32_32x32x16_bf16(k0, qf[0][dstep], s00, 0, 0, 0);
        s01 = __builtin_amdgcn_mfma_f32_32x32x16_bf16(k1, qf[0][dstep], s01, 0, 0, 0);
        s10 = __builtin_amdgcn_mfma_f32_32x32x16_bf16(k0, qf[1][dstep], s10, 0, 0, 0);
        s11 = __builtin_amdgcn_mfma_f32_32x32x16_bf16(k1, qf[1][dstep], s11, 0, 0, 0);
      }
    }
    if (t == qt) {  // diagonal tile masks
#pragma unroll
      for (int r = 0; r < 16; ++r) {
        int kb = (r & 3) + 8 * (r >> 2) + (hi << 2);
        if (kb > l31) { s00[r] = -3e38f; s11[r] = -3e38f; }
        s01[r] = -3e38f;
      }
    }
#pragma unroll
    for (int r = 0; r < 16; ++r) {
      s00[r] = __builtin_amdgcn_exp2f(s00[r]);
      s01[r] = __builtin_amdgcn_exp2f(s01[r]);
      s10[r] = __builtin_amdgcn_exp2f(s10[r]);
      s11[r] = __builtin_amdgcn_exp2f(s11[r]);
    }
    {
      float a0 = 0.f, a1 = 0.f, a2 = 0.f, a3 = 0.f;
      float b0 = 0.f, b1 = 0.f, b2 = 0.f, b3 = 0.f;
#pragma unroll
      for (int r = 0; r < 16; r += 4) {
        a0 += s00[r]; a1 += s00[r + 1]; a2 += s00[r + 2]; a3 += s00[r + 3];
        a0 += s01[r]; a1 += s01[r + 1]; a2 += s01[r + 2]; a3 += s01[r + 3];
        b0 += s10[r]; b1 += s10[r + 1]; b2 += s10[r + 2]; b3 += s10[r + 3];
        b0 += s11[r]; b1 += s11[r + 1]; b2 += s11[r + 2]; b3 += s11[r + 3];
      }
      l0 += (a0 + a1) + (a2 + a3);
      l1 += (b0 + b1) + (b2 + b3);
    }
    bf16x8 pf0[4], pf1[4];
    {
      unsigned wd[8];
#pragma unroll
      for (int i = 0; i < 8; ++i) wd[i] = cvt_pk_bf16(s00[2 * i], s00[2 * i + 1]);
      permswap(wd[0], wd[2]); permswap(wd[1], wd[3]);
      permswap(wd[4], wd[6]); permswap(wd[5], wd[7]);
      pf0[0] = pack4(wd[0], wd[1], wd[2], wd[3]);
      pf0[1] = pack4(wd[4], wd[5], wd[6], wd[7]);
#pragma unroll
      for (int i = 0; i < 8; ++i) wd[i] = cvt_pk_bf16(s01[2 * i], s01[2 * i + 1]);
      permswap(wd[0], wd[2]); permswap(wd[1], wd[3]);
      permswap(wd[4], wd[6]); permswap(wd[5], wd[7]);
      pf0[2] = pack4(wd[0], wd[1], wd[2], wd[3]);
      pf0[3] = pack4(wd[4], wd[5], wd[6], wd[7]);
#pragma unroll
      for (int i = 0; i < 8; ++i) wd[i] = cvt_pk_bf16(s10[2 * i], s10[2 * i + 1]);
      permswap(wd[0], wd[2]); permswap(wd[1], wd[3]);
      permswap(wd[4], wd[6]); permswap(wd[5], wd[7]);
      pf1[0] = pack4(wd[0], wd[1], wd[2], wd[3]);
      pf1[1] = pack4(wd[4], wd[5], wd[6], wd[7]);
#pragma unroll
      for (int i = 0; i < 8; ++i) wd[i] = cvt_pk_bf16(s11[2 * i], s11[2 * i + 1]);
      permswap(wd[0], wd[2]); permswap(wd[1], wd[3]);
      permswap(wd[4], wd[6]); permswap(wd[5], wd[7]);
      pf1[2] = pack4(wd[0], wd[1], wd[2], wd[3]);
      pf1[3] = pack4(wd[4], wd[5], wd[6], wd[7]);
    }
    {
      const char* vb0 = (const char*)Vs[cur] + (size_t)l31 * 128;
      const char* vb1 = vb0 + 4096;
#pragma unroll
      for (int ks = 0; ks < 4; ++ks) {
        int cb = ks * 32 + (hi << 4);
        bf16x8 v0 = *(const bf16x8*)(vb0 + (cb ^ rx));
        bf16x8 v1 = *(const bf16x8*)(vb1 + (cb ^ rx));
        acc00 = __builtin_amdgcn_mfma_f32_32x32x16_bf16(v0, pf0[ks], acc00, 0, 0, 0);
        acc01 = __builtin_amdgcn_mfma_f32_32x32x16_bf16(v1, pf0[ks], acc01, 0, 0, 0);
        acc10 = __builtin_amdgcn_mfma_f32_32x32x16_bf16(v0, pf1[ks], acc10, 0, 0, 0);
        acc11 = __builtin_amdgcn_mfma_f32_32x32x16_bf16(v1, pf1[ks], acc11, 0, 0, 0);
      }
    }
    __syncthreads();
  }

  l0 += __shfl_xor(l0, 32);
  l1 += __shfl_xor(l1, 32);
  float inv0 = 1.f / l0, inv1 = 1.f / l1;
  size_t orow0 = ((size_t)(b * S_LEN + qt * 64 + l31)) * EMB + h * HDIM;
  size_t orow1 = orow0 + (size_t)32 * EMB;
#pragma unroll
  for (int r = 0; r < 16; r += 2) {
    int d = (r & 3) + 8 * (r >> 2) + (hi << 2);
    unsigned w00 = cvt_pk_bf16(acc00[r] * inv0, acc00[r + 1] * inv0);
    unsigned w01 = cvt_pk_bf16(acc01[r] * inv0, acc01[r + 1] * inv0);
    unsigned w10 = cvt_pk_bf16(acc10[r] * inv1, acc10[r + 1] * inv1);
    unsigned w11 = cvt_pk_bf16(acc11[r] * inv1, acc11[r + 1] * inv1);
    *(unsigned*)((char*)ctx + (orow0 + d) * 2) = w00;
    *(unsigned*)((char*)ctx + (orow0 + 32 + d) * 2) = w01;
    *(unsigned*)((char*)ctx + (orow1 + d) * 2) = w10;
    *(unsigned*)((char*)ctx + (orow1 + 32 + d) * 2) = w11;
  }
}

extern "C" void kernel_launch(void* const* d_in, const int* in_sizes, int n_in,
                              void* d_out, int out_size, void* d_ws, size_t ws_size,
                              hipStream_t stream) {
  const float* x = (const float*)d_in[0];
  const int* pos = (const int*)d_in[1];
  const float* Wq = (const float*)d_in[3];
  const float* Wk = (const float*)d_in[4];
  const float* Wv = (const float*)d_in[5];
  const float* Wo = (const float*)d_in[6];
  const float* qw = (const float*)d_in[7];
  const float* kw = (const float*)d_in[8];

  float* out = (float*)d_out;
  float* Kc = out + (size_t)2 * 2048 * 2048;
  float* Vc = Kc + (size_t)2 * 8 * 2048 * 64;

  char* ws = (char*)d_ws;
  size_t off = 0;
  auto alloc = [&](size_t bytes) {
    char* p = ws + off;
    off += (bytes + 255) & ~(size_t)255;
    return (void*)p;
  };
  __bf16* xb = (__bf16*)alloc((size_t)4096 * 2048 * 2);
  __bf16* Wcat = (__bf16*)alloc((size_t)3072 * 2048 * 2);
  __bf16* Wot = (__bf16*)alloc((size_t)2048 * 2048 * 2);
  __bf16* QKV = (__bf16*)alloc((size_t)4096 * 3072 * 2);
  __bf16* ctx = (__bf16*)alloc((size_t)4096 * 2048 * 2);
  __bf16* Katt = (__bf16*)alloc((size_t)2 * 8 * 2048 * 64 * 2);
  __bf16* Vtat = (__bf16*)alloc((size_t)2 * 8 * 2048 * 64 * 2);
  float* cosT = (float*)alloc((size_t)2048 * 32 * 4);
  float* sinT = (float*)alloc((size_t)2048 * 32 * 4);

  prep_kernel<<<7168, 256, 0, stream>>>(x, xb, Wq, Wk, Wv, Wo, Wcat, Wot, cosT, sinT);
  gemm4w_kernel<128, 192, __bf16><<<512, 256, 0, stream>>>(xb, Wcat, QKV, 4096, 3072, 2048);
  kvrope_kernel<<<4096, 256, 0, stream>>>(QKV, pos, kw, cosT, sinT, Katt, Vtat, Kc, Vc);
  attn_kernel<<<512, 256, 0, stream>>>(QKV, pos, qw, cosT, sinT, Katt, Vtat, ctx);
  gemm4w_kernel<128, 128, float><<<512, 256, 0, stream>>>(ctx, Wot, out, 4096, 2048, 2048);
}

// Round 18
// 160.857 us; speedup vs baseline: 1.1246x; 1.0506x over previous
//
#include <hip/hip_runtime.h>
#include <stdint.h>

#define S_LEN 2048
#define EMB 2048
#define NHEADS 32
#define NKVH 8
#define HDIM 64

typedef float f32x4 __attribute__((ext_vector_type(4)));
typedef float f32x16 __attribute__((ext_vector_type(16)));
typedef __bf16 bf16x8 __attribute__((ext_vector_type(8)));
typedef unsigned int u32x4 __attribute__((ext_vector_type(4)));

typedef const __attribute__((address_space(1))) void* as1cv;
typedef __attribute__((address_space(3))) void* as3v;

__device__ __forceinline__ void gload_lds16(const void* g, void* l) {
  as1cv gp = (as1cv)(uintptr_t)g;
  as3v lp = (as3v)(uintptr_t)l;
  __builtin_amdgcn_global_load_lds(gp, lp, 16, 0, 0);
}

__device__ __forceinline__ unsigned cvt_pk_bf16(float lo, float hi) {
  unsigned r;
  asm("v_cvt_pk_bf16_f32 %0, %1, %2" : "=v"(r) : "v"(lo), "v"(hi));
  return r;
}

__device__ __forceinline__ void permswap(unsigned& a, unsigned& b) {
  asm("v_permlane32_swap_b32 %0, %1" : "+v"(a), "+v"(b));
}

__device__ __forceinline__ bf16x8 pack4(unsigned a, unsigned b, unsigned c, unsigned d) {
  union { u32x4 u; bf16x8 f; } x;
  x.u = (u32x4){a, b, c, d};
  return x.f;
}

// ------- fused preprocessing: cast x->bf16 + 4 transpose-casts + RoPE table ----------
__global__ __launch_bounds__(256) void prep_kernel(const float* __restrict__ x,
                                                   __bf16* __restrict__ xb,
                                                   const float* __restrict__ Wq,
                                                   const float* __restrict__ Wk,
                                                   const float* __restrict__ Wv,
                                                   const float* __restrict__ Wo,
                                                   __bf16* __restrict__ Wcat,
                                                   __bf16* __restrict__ Wot,
                                                   float* __restrict__ cosT,
                                                   float* __restrict__ sinT) {
  int bid = blockIdx.x;
  int tid = threadIdx.x;
  if (bid < 4096) {
    int i = bid * 256 + tid;
    f32x4 a = *(const f32x4*)(x + (size_t)i * 8);
    f32x4 b = *(const f32x4*)(x + (size_t)i * 8 + 4);
    bf16x8 o;
    o[0] = (__bf16)a[0]; o[1] = (__bf16)a[1]; o[2] = (__bf16)a[2]; o[3] = (__bf16)a[3];
    o[4] = (__bf16)b[0]; o[5] = (__bf16)b[1]; o[6] = (__bf16)b[2]; o[7] = (__bf16)b[3];
    *(bf16x8*)(xb + (size_t)i * 8) = o;
    return;
  }
  if (bid >= 6656) {  // RoPE table
    int p = (bid - 6656) * 4 + (tid >> 6);
    int i = tid & 63;
    if (i < 32) {
      float inv = powf(10000.0f, -(float)i / 32.0f);
      float ang = (float)p * inv;
      cosT[p * 32 + i] = cosf(ang);
      sinT[p * 32 + i] = sinf(ang);
    }
    return;
  }
  int lb = bid - 4096;
  const float* in;
  __bf16* out;
  int C, bx, by;
  if (lb < 1024) {
    in = Wq; out = Wcat; C = 2048; bx = lb & 31; by = lb >> 5;
  } else if (lb < 1280) {
    lb -= 1024;
    in = Wk; out = Wcat + (size_t)2048 * 2048; C = 512; bx = lb & 7; by = lb >> 3;
  } else if (lb < 1536) {
    lb -= 1280;
    in = Wv; out = Wcat + (size_t)2560 * 2048; C = 512; bx = lb & 7; by = lb >> 3;
  } else {
    lb -= 1536;
    in = Wo; out = Wot; C = 2048; bx = lb & 31; by = lb >> 5;
  }
  const int R = 2048;
  __shared__ float t[64][65];
  int c0 = bx * 64, r0 = by * 64;
#pragma unroll
  for (int i = 0; i < 16; ++i) {
    int e = i * 256 + tid;
    int rr = e >> 6, cc = e & 63;
    t[rr][cc] = in[(size_t)(r0 + rr) * C + c0 + cc];
  }
  __syncthreads();
  // paired 4B stores (2 bf16) for full write-coalescing
#pragma unroll
  for (int i = 0; i < 8; ++i) {
    int e = i * 256 + tid;
    int rr = e >> 5, cc = (e & 31) << 1;
    unsigned v = cvt_pk_bf16(t[cc][rr], t[cc + 1][rr]);
    *(unsigned*)((char*)(out + (size_t)(c0 + rr) * R + r0 + cc)) = v;
  }
}

// ====== 4-wave, 2-blocks/CU, 2-phase dbuf bf16 TN GEMM (512-WG grids) ======
template <int BM, int BN, typename OUT>
__global__ __launch_bounds__(256, 2) void gemm4w_kernel(const __bf16* __restrict__ A,
                                                        const __bf16* __restrict__ B,
                                                        OUT* __restrict__ C,
                                                        int M, int N, int K) {
  constexpr int MF = (BM / 2) / 16;
  constexpr int NF = (BN / 2) / 16;
  constexpr int ROWS = BM + BN;
  constexpr int NCALL = ROWS / 32;
  constexpr int CHA = BM / 32;
  __shared__ __align__(16) __bf16 sm[2][ROWS * 64];

  const int NT = K >> 6;
  const int nt = N / BN;
  const int nwg = (M / BM) * nt;
  const int q8 = nwg >> 3;
  int wg = blockIdx.x;
  int swz = (wg & 7) * q8 + (wg >> 3);
  int bm = swz / nt, bn = swz % nt;
  size_t m0 = (size_t)bm * BM, n0 = (size_t)bn * BN;

  int tid = threadIdx.x;
  int L = tid & 63, w = tid >> 6;
  int wrow = w >> 1, wcol = w & 1;
  int l15 = L & 15, hi2 = L >> 4;
  int lx = (l15 & 7) << 4;
  const int cx0 = (hi2 << 4) ^ lx;
  const int cx1 = (64 + (hi2 << 4)) ^ lx;

  int srow = tid >> 3;
  int scol = ((tid & 7) ^ (srow & 7)) << 3;
  const __bf16* pA = A + (size_t)(m0 + srow) * K + scol;
  const __bf16* pB = B + (size_t)(n0 + srow) * K + scol;

  char* smb = (char*)sm;
  const int aRow = (wrow * (BM / 2) + l15) * 128;
  const int bRow = (BM + wcol * (BN / 2) + l15) * 128;

  f32x4 acc[MF][NF];
#pragma unroll
  for (int m = 0; m < MF; ++m)
#pragma unroll
    for (int n = 0; n < NF; ++n) acc[m][n] = (f32x4){0.f, 0.f, 0.f, 0.f};

  auto STG = [&](int buf, int c, int t) {
    const __bf16* s = (c < CHA) ? pA + (size_t)(c << 5) * K + ((size_t)t << 6)
                                : pB + (size_t)((c - CHA) << 5) * K + ((size_t)t << 6);
    gload_lds16(s, smb + buf * (ROWS * 128) + c * 4096 + tid * 16);
  };

#pragma unroll
  for (int c = 0; c < NCALL; ++c) STG(0, c, 0);
#pragma unroll
  for (int c = 0; c < NCALL; ++c) STG(1, c, 1);
  if constexpr (NCALL == 10) asm volatile("s_waitcnt vmcnt(10)" ::: "memory");
  else asm volatile("s_waitcnt vmcnt(8)" ::: "memory");
  __builtin_amdgcn_s_barrier();

  for (int t = 0; t < NT; ++t) {
    const char* aC = smb + (t & 1) * (ROWS * 128);
    bf16x8 af[MF][2], bf[NF][2];
#pragma unroll
    for (int n = 0; n < NF; ++n) {
      bf[n][0] = *(const bf16x8*)(aC + bRow + n * 2048 + cx0);
      bf[n][1] = *(const bf16x8*)(aC + bRow + n * 2048 + cx1);
    }
#pragma unroll
    for (int m = 0; m < MF; ++m) {
      af[m][0] = *(const bf16x8*)(aC + aRow + m * 2048 + cx0);
      af[m][1] = *(const bf16x8*)(aC + aRow + m * 2048 + cx1);
    }
    asm volatile("s_waitcnt lgkmcnt(4)" ::: "memory");
    __builtin_amdgcn_sched_barrier(0);
    __builtin_amdgcn_s_setprio(1);
#pragma unroll
    for (int m = 0; m < MF / 2; ++m)
#pragma unroll
      for (int n = 0; n < NF; ++n)
#pragma unroll
        for (int kk = 0; kk < 2; ++kk)
          acc[m][n] = __builtin_amdgcn_mfma_f32_16x16x32_bf16(
              kk ? af[m][1] : af[m][0], kk ? bf[n][1] : bf[n][0], acc[m][n], 0, 0, 0);
    __builtin_amdgcn_s_setprio(0);
    asm volatile("s_waitcnt lgkmcnt(0)" ::: "memory");
    __builtin_amdgcn_sched_barrier(0);
    __builtin_amdgcn_s_barrier();
    if (t + 2 < NT) {
#pragma unroll
      for (int c = 0; c < NCALL; ++c) STG(t & 1, c, t + 2);
    }
    __builtin_amdgcn_s_setprio(1);
#pragma unroll
    for (int m = MF / 2; m < MF; ++m)
#pragma unroll
      for (int n = 0; n < NF; ++n)
#pragma unroll
        for (int kk = 0; kk < 2; ++kk)
          acc[m][n] = __builtin_amdgcn_mfma_f32_16x16x32_bf16(
              kk ? af[m][1] : af[m][0], kk ? bf[n][1] : bf[n][0], acc[m][n], 0, 0, 0);
    __builtin_amdgcn_s_setprio(0);
    if (t + 2 < NT) {
      if constexpr (NCALL == 10) asm volatile("s_waitcnt vmcnt(10)" ::: "memory");
      else asm volatile("s_waitcnt vmcnt(8)" ::: "memory");
    } else if (t + 1 < NT) {
      asm volatile("s_waitcnt vmcnt(0)" ::: "memory");
    }
    __builtin_amdgcn_s_barrier();
  }

#pragma unroll
  for (int m = 0; m < MF; ++m)
#pragma unroll
    for (int n = 0; n < NF; ++n)
#pragma unroll
      for (int r = 0; r < 4; ++r)
        C[(m0 + wrow * (BM / 2) + m * 16 + (hi2 << 2) + r) * (size_t)N + n0 +
          wcol * (BN / 2) + n * 16 + l15] = (OUT)acc[m][n][r];
}

// ------- K/V RMSNorm + RoPE + layout v2: 16-token s-tiles, LDS V-transpose -------
// grid 256 = b(2) x stile(128). Block = 4 waves; wave w handles tokens {w,w+4,w+8,w+12}.
// K path identical math to v1 (coalesced). V^T goes through LDS so Vtatt is written in
// 32B-contiguous runs per (g,d) row (16x line efficiency vs per-token 2B scatter).
__global__ __launch_bounds__(256) void kvrope_kernel(
    const __bf16* __restrict__ QKV, const int* __restrict__ pos,
    const float* __restrict__ kw,
    const float* __restrict__ cosT, const float* __restrict__ sinT,
    __bf16* __restrict__ Katt, __bf16* __restrict__ Vtatt,
    float* __restrict__ Kc, float* __restrict__ Vc) {
  __shared__ __bf16 vt[8][64][16];  // [g][d][s_local], 16 KB
  int bid = blockIdx.x;
  int b = bid >> 7, st = bid & 127;
  int s0 = st * 16;
  int tid = threadIdx.x, lane = tid & 63, w = tid >> 6;
  float kwl = kw[lane];
  int i31 = lane & 31;

#pragma unroll
  for (int i = 0; i < 4; ++i) {
    int sl = (i << 2) | w;
    int s = s0 + sl;
    int token = b * S_LEN + s;
    int p = pos[token];
    float cs = cosT[p * 32 + i31], sn = sinT[p * 32 + i31];
    const __bf16* base = QKV + (size_t)token * 3072;
#pragma unroll
    for (int g = 0; g < 8; ++g) {
      float v = (float)base[2048 + g * 64 + lane];
      float ss = v * v;
#pragma unroll
      for (int m = 1; m < 64; m <<= 1) ss += __shfl_xor(ss, m);
      float xn = v * rsqrtf(ss * (1.0f / 64.0f) + 1e-6f) * kwl;
      float other = __shfl_xor(xn, 32);
      float o = xn * cs + ((lane < 32) ? -other * sn : other * sn);
      size_t kidx = ((size_t)(b * NKVH + g) * S_LEN + s) * HDIM + lane;
      Katt[kidx] = (__bf16)o;
      Kc[kidx] = o;
    }
#pragma unroll
    for (int g = 0; g < 8; ++g) {
      float v = (float)base[2560 + g * 64 + lane];
      Vc[((size_t)(b * NKVH + g) * S_LEN + s) * HDIM + lane] = v;
      vt[g][lane][sl] = (__bf16)v;
    }
  }
  __syncthreads();
  // emit V^T: thread owns rows (g = w, w+4; d = lane), 32B contiguous each
#pragma unroll
  for (int r = 0; r < 2; ++r) {
    int g = (r << 2) | w;
    __bf16* dst = Vtatt + ((size_t)(b * NKVH + g) * HDIM + lane) * S_LEN + s0;
    *(f32x4*)dst = *(const f32x4*)&vt[g][lane][0];
    *(f32x4*)(dst + 8) = *(const f32x4*)&vt[g][lane][8];
  }
}

// ---------------- causal GQA flash attention + fused Q RMSNorm/RoPE prologue ----------
__global__ __launch_bounds__(256, 2) void attn_kernel(const __bf16* __restrict__ QKV,
                                                      const int* __restrict__ pos,
                                                      const float* __restrict__ qw,
                                                      const float* __restrict__ cosT,
                                                      const float* __restrict__ sinT,
                                                      const __bf16* __restrict__ Katt,
                                                      const __bf16* __restrict__ Vtatt,
                                                      __bf16* __restrict__ ctx) {
  __shared__ __align__(16) __bf16 Ks[2][4096];
  __shared__ __align__(16) __bf16 Vs[2][4096];
  int bid = blockIdx.x;
  int qt, bg;
  if (bid < 256) { qt = 31 - (bid >> 4); bg = bid & 15; }  // CU gets qt pair summing 31
  else { qt = (bid - 256) >> 4; bg = bid & 15; }
  int b = bg >> 3, g = bg & 7;
  int tid = threadIdx.x, lane = tid & 63, w = tid >> 6;
  int l31 = lane & 31, hi = lane >> 5;
  int h = g * 4 + w;

  const __bf16* Kg = Katt + (size_t)bg * (S_LEN * HDIM);
  const __bf16* Vg = Vtatt + (size_t)bg * (HDIM * S_LEN);

  int sr = tid >> 3;
  int sc = ((tid & 7) ^ (sr & 7)) << 3;
  const __bf16* Ksrc = Kg + (size_t)sr * HDIM + sc;
  const __bf16* Vsrc = Vg + (size_t)sr * S_LEN + sc;

  gload_lds16(Ksrc, &Ks[0][tid * 8]);
  gload_lds16(Ksrc + 32 * HDIM, &Ks[0][2048 + tid * 8]);
  gload_lds16(Vsrc, &Vs[0][tid * 8]);
  gload_lds16(Vsrc + (size_t)32 * S_LEN, &Vs[0][2048 + tid * 8]);

  // ---- fused Q prologue: raw QKV -> normalized, roped, scaled bf16 B-fragments ----
  const float qscale = 0.18033688011112042f;  // 0.125 * log2(e)
  float qwf[4][8];
#pragma unroll
  for (int ds = 0; ds < 4; ++ds) {
    *(f32x4*)&qwf[ds][0] = *(const f32x4*)(qw + ds * 16 + (hi << 3));
    *(f32x4*)&qwf[ds][4] = *(const f32x4*)(qw + ds * 16 + (hi << 3) + 4);
  }
  bf16x8 qf[2][4];
#pragma unroll
  for (int qs = 0; qs < 2; ++qs) {
    int row = qt * 64 + qs * 32 + l31;
    const __bf16* qr = QKV + ((size_t)(b * S_LEN + row)) * 3072 + h * 64;
    float v[4][8];
    float ss = 0.f;
#pragma unroll
    for (int ds = 0; ds < 4; ++ds) {
      bf16x8 a = *(const bf16x8*)(qr + ds * 16 + (hi << 3));
#pragma unroll
      for (int j = 0; j < 8; ++j) {
        v[ds][j] = (float)a[j];
        ss += v[ds][j] * v[ds][j];
      }
    }
    ss += __shfl_xor(ss, 32);
    float rr = rsqrtf(ss * (1.0f / 64.0f) + 1e-6f) * qscale;
    int p = pos[b * S_LEN + row];
    const float* cb = cosT + p * 32 + (hi << 3);
    const float* sb = sinT + p * 32 + (hi << 3);
    float cl[8], ch[8], sl[8], sh[8];
    *(f32x4*)&cl[0] = *(const f32x4*)cb;        *(f32x4*)&cl[4] = *(const f32x4*)(cb + 4);
    *(f32x4*)&ch[0] = *(const f32x4*)(cb + 16); *(f32x4*)&ch[4] = *(const f32x4*)(cb + 20);
    *(f32x4*)&sl[0] = *(const f32x4*)sb;        *(f32x4*)&sl[4] = *(const f32x4*)(sb + 4);
    *(f32x4*)&sh[0] = *(const f32x4*)(sb + 16); *(f32x4*)&sh[4] = *(const f32x4*)(sb + 20);
    float o[4][8];
#pragma unroll
    for (int j = 0; j < 8; ++j) {
      float x0 = v[0][j] * rr * qwf[0][j];
      float x1 = v[1][j] * rr * qwf[1][j];
      float x2 = v[2][j] * rr * qwf[2][j];
      float x3 = v[3][j] * rr * qwf[3][j];
      o[0][j] = x0 * cl[j] - x2 * sl[j];
      o[1][j] = x1 * ch[j] - x3 * sh[j];
      o[2][j] = x2 * cl[j] + x0 * sl[j];
      o[3][j] = x3 * ch[j] + x1 * sh[j];
    }
#pragma unroll
    for (int ds = 0; ds < 4; ++ds)
      qf[qs][ds] = pack4(cvt_pk_bf16(o[ds][0], o[ds][1]), cvt_pk_bf16(o[ds][2], o[ds][3]),
                         cvt_pk_bf16(o[ds][4], o[ds][5]), cvt_pk_bf16(o[ds][6], o[ds][7]));
  }

  f32x16 acc00, acc01, acc10, acc11;  // [qsub][dblock], O^T[d][q]
#pragma unroll
  for (int r = 0; r < 16; ++r) { acc00[r] = 0.f; acc01[r] = 0.f; acc10[r] = 0.f; acc11[r] = 0.f; }
  float l0 = 0.f, l1 = 0.f;

  __syncthreads();

  int rx = (l31 & 7) << 4;

  for (int t = 0; t <= qt; ++t) {
    int cur = t & 1;
    if (t < qt) {
      const __bf16* kn = Ksrc + (size_t)(t + 1) * (64 * HDIM);
      const __bf16* vn = Vsrc + (size_t)(t + 1) * 64;
      gload_lds16(kn, &Ks[cur ^ 1][tid * 8]);
      gload_lds16(kn + 32 * HDIM, &Ks[cur ^ 1][2048 + tid * 8]);
      gload_lds16(vn, &Vs[cur ^ 1][tid * 8]);
      gload_lds16(vn + (size_t)32 * S_LEN, &Vs[cur ^ 1][2048 + tid * 8]);
    }
    // QK^T swapped: S^T[kv][q] = K x Q ; shared K-frag reads feed both q-subtiles
    f32x16 s00, s01, s10, s11;
#pragma unroll
    for (int r = 0; r < 16; ++r) { s00[r] = 0.f; s01[r] = 0.f; s10[r] = 0.f; s11[r] = 0.f; }
    {
      const char* kb0 = (const char*)Ks[cur] + (size_t)l31 * 128;
      const char* kb1 = kb0 + 4096;
#pragma unroll
      for (int dstep = 0; dstep < 4; ++dstep) {
        int cb = dstep * 32 + (hi << 4);
        bf16x8 k0 = *(const bf16x8*)(kb0 + (cb ^ rx));
        bf16x8 k1 = *(const bf16x8*)(kb1 + (cb ^ rx));
        s00 = __builtin_amdgcn_mfma_f32_32x32x16_bf16(k0, qf[0][dstep], s00, 0, 0, 0);
        s01 = __builtin_amdgcn_mfma_f32_32x32x16_bf16(k1, qf[0][dstep], s01, 0, 0, 0);
        s10 = __builtin_amdgcn_mfma_f32_32x32x16_bf16(k0, qf[1][dstep], s10, 0, 0, 0);
        s11 = __builtin_amdgcn_mfma_f32_32x32x16_bf16(k1, qf[1][dstep], s11, 0, 0, 0);
      }
    }
    if (t == qt) {  // diagonal tile masks
#pragma unroll
      for (int r = 0; r < 16; ++r) {
        int kb = (r & 3) + 8 * (r >> 2) + (hi << 2);
        if (kb > l31) { s00[r] = -3e38f; s11[r] = -3e38f; }
        s01[r] = -3e38f;
      }
    }
#pragma unroll
    for (int r = 0; r < 16; ++r) {
      s00[r] = __builtin_amdgcn_exp2f(s00[r]);
      s01[r] = __builtin_amdgcn_exp2f(s01[r]);
      s10[r] = __builtin_amdgcn_exp2f(s10[r]);
      s11[r] = __builtin_amdgcn_exp2f(s11[r]);
    }
    {
      float a0 = 0.f, a1 = 0.f, a2 = 0.f, a3 = 0.f;
      float b0 = 0.f, b1 = 0.f, b2 = 0.f, b3 = 0.f;
#pragma unroll
      for (int r = 0; r < 16; r += 4) {
        a0 += s00[r]; a1 += s00[r + 1]; a2 += s00[r + 2]; a3 += s00[r + 3];
        a0 += s01[r]; a1 += s01[r + 1]; a2 += s01[r + 2]; a3 += s01[r + 3];
        b0 += s10[r]; b1 += s10[r + 1]; b2 += s10[r + 2]; b3 += s10[r + 3];
        b0 += s11[r]; b1 += s11[r + 1]; b2 += s11[r + 2]; b3 += s11[r + 3];
      }
      l0 += (a0 + a1) + (a2 + a3);
      l1 += (b0 + b1) + (b2 + b3);
    }
    bf16x8 pf0[4], pf1[4];
    {
      unsigned wd[8];
#pragma unroll
      for (int i = 0; i < 8; ++i) wd[i] = cvt_pk_bf16(s00[2 * i], s00[2 * i + 1]);
      permswap(wd[0], wd[2]); permswap(wd[1], wd[3]);
      permswap(wd[4], wd[6]); permswap(wd[5], wd[7]);
      pf0[0] = pack4(wd[0], wd[1], wd[2], wd[3]);
      pf0[1] = pack4(wd[4], wd[5], wd[6], wd[7]);
#pragma unroll
      for (int i = 0; i < 8; ++i) wd[i] = cvt_pk_bf16(s01[2 * i], s01[2 * i + 1]);
      permswap(wd[0], wd[2]); permswap(wd[1], wd[3]);
      permswap(wd[4], wd[6]); permswap(wd[5], wd[7]);
      pf0[2] = pack4(wd[0], wd[1], wd[2], wd[3]);
      pf0[3] = pack4(wd[4], wd[5], wd[6], wd[7]);
#pragma unroll
      for (int i = 0; i < 8; ++i) wd[i] = cvt_pk_bf16(s10[2 * i], s10[2 * i + 1]);
      permswap(wd[0], wd[2]); permswap(wd[1], wd[3]);
      permswap(wd[4], wd[6]); permswap(wd[5], wd[7]);
      pf1[0] = pack4(wd[0], wd[1], wd[2], wd[3]);
      pf1[1] = pack4(wd[4], wd[5], wd[6], wd[7]);
#pragma unroll
      for (int i = 0; i < 8; ++i) wd[i] = cvt_pk_bf16(s11[2 * i], s11[2 * i + 1]);
      permswap(wd[0], wd[2]); permswap(wd[1], wd[3]);
      permswap(wd[4], wd[6]); permswap(wd[5], wd[7]);
      pf1[2] = pack4(wd[0], wd[1], wd[2], wd[3]);
      pf1[3] = pack4(wd[4], wd[5], wd[6], wd[7]);
    }
    {
      const char* vb0 = (const char*)Vs[cur] + (size_t)l31 * 128;
      const char* vb1 = vb0 + 4096;
#pragma unroll
      for (int ks = 0; ks < 4; ++ks) {
        int cb = ks * 32 + (hi << 4);
        bf16x8 v0 = *(const bf16x8*)(vb0 + (cb ^ rx));
        bf16x8 v1 = *(const bf16x8*)(vb1 + (cb ^ rx));
        acc00 = __builtin_amdgcn_mfma_f32_32x32x16_bf16(v0, pf0[ks], acc00, 0, 0, 0);
        acc01 = __builtin_amdgcn_mfma_f32_32x32x16_bf16(v1, pf0[ks], acc01, 0, 0, 0);
        acc10 = __builtin_amdgcn_mfma_f32_32x32x16_bf16(v0, pf1[ks], acc10, 0, 0, 0);
        acc11 = __builtin_amdgcn_mfma_f32_32x32x16_bf16(v1, pf1[ks], acc11, 0, 0, 0);
      }
    }
    __syncthreads();
  }

  l0 += __shfl_xor(l0, 32);
  l1 += __shfl_xor(l1, 32);
  float inv0 = 1.f / l0, inv1 = 1.f / l1;
  size_t orow0 = ((size_t)(b * S_LEN + qt * 64 + l31)) * EMB + h * HDIM;
  size_t orow1 = orow0 + (size_t)32 * EMB;
#pragma unroll
  for (int r = 0; r < 16; r += 2) {
    int d = (r & 3) + 8 * (r >> 2) + (hi << 2);
    unsigned w00 = cvt_pk_bf16(acc00[r] * inv0, acc00[r + 1] * inv0);
    unsigned w01 = cvt_pk_bf16(acc01[r] * inv0, acc01[r + 1] * inv0);
    unsigned w10 = cvt_pk_bf16(acc10[r] * inv1, acc10[r + 1] * inv1);
    unsigned w11 = cvt_pk_bf16(acc11[r] * inv1, acc11[r + 1] * inv1);
    *(unsigned*)((char*)ctx + (orow0 + d) * 2) = w00;
    *(unsigned*)((char*)ctx + (orow0 + 32 + d) * 2) = w01;
    *(unsigned*)((char*)ctx + (orow1 + d) * 2) = w10;
    *(unsigned*)((char*)ctx + (orow1 + 32 + d) * 2) = w11;
  }
}

extern "C" void kernel_launch(void* const* d_in, const int* in_sizes, int n_in,
                              void* d_out, int out_size, void* d_ws, size_t ws_size,
                              hipStream_t stream) {
  const float* x = (const float*)d_in[0];
  const int* pos = (const int*)d_in[1];
  const float* Wq = (const float*)d_in[3];
  const float* Wk = (const float*)d_in[4];
  const float* Wv = (const float*)d_in[5];
  const float* Wo = (const float*)d_in[6];
  const float* qw = (const float*)d_in[7];
  const float* kw = (const float*)d_in[8];

  float* out = (float*)d_out;
  float* Kc = out + (size_t)2 * 2048 * 2048;
  float* Vc = Kc + (size_t)2 * 8 * 2048 * 64;

  char* ws = (char*)d_ws;
  size_t off = 0;
  auto alloc = [&](size_t bytes) {
    char* p = ws + off;
    off += (bytes + 255) & ~(size_t)255;
    return (void*)p;
  };
  __bf16* xb = (__bf16*)alloc((size_t)4096 * 2048 * 2);
  __bf16* Wcat = (__bf16*)alloc((size_t)3072 * 2048 * 2);
  __bf16* Wot = (__bf16*)alloc((size_t)2048 * 2048 * 2);
  __bf16* QKV = (__bf16*)alloc((size_t)4096 * 3072 * 2);
  __bf16* ctx = (__bf16*)alloc((size_t)4096 * 2048 * 2);
  __bf16* Katt = (__bf16*)alloc((size_t)2 * 8 * 2048 * 64 * 2);
  __bf16* Vtat = (__bf16*)alloc((size_t)2 * 8 * 2048 * 64 * 2);
  float* cosT = (float*)alloc((size_t)2048 * 32 * 4);
  float* sinT = (float*)alloc((size_t)2048 * 32 * 4);

  prep_kernel<<<7168, 256, 0, stream>>>(x, xb, Wq, Wk, Wv, Wo, Wcat, Wot, cosT, sinT);
  gemm4w_kernel<128, 192, __bf16><<<512, 256, 0, stream>>>(xb, Wcat, QKV, 4096, 3072, 2048);
  kvrope_kernel<<<256, 256, 0, stream>>>(QKV, pos, kw, cosT, sinT, Katt, Vtat, Kc, Vc);
  attn_kernel<<<512, 256, 0, stream>>>(QKV, pos, qw, cosT, sinT, Katt, Vtat, ctx);
  gemm4w_kernel<128, 128, float><<<512, 256, 0, stream>>>(ctx, Wot, out, 4096, 2048, 2048);
}